// Round 25
// baseline (117.107 us; speedup 1.0000x reference)
//
#include <hip/hip_runtime.h>
#include <hip/hip_bf16.h>

#define SS 512
#define BATCH 2048
#define GL 32
#define OL 20
#define MM 32
#define CC 16
#define GM 64
#define OM 20
#define GR 128
#define ORR 38
#define IMID 384
#define IROOT 768
#define EPSBN 1e-5f

#define KSPLIT 16
#define KCH 48            // 768 / 16

// ---- workspace layout (floats; child fp32) ----
#define SZ_CHILD ((size_t)SS * OL * BATCH)
#define OFF_SCL  (SZ_CHILD)
#define OFF_SHL  (OFF_SCL + (size_t)SS * OL)
#define OFF_HM   (OFF_SHL + (size_t)SS * OL)
#define OFF_MP   (OFF_HM + (size_t)MM * OM * BATCH)
#define OFF_HR   (OFF_MP + (size_t)MM * 32 * 2 * OM)
#define OFF_RP   (OFF_HR + (size_t)BATCH * ORR)
#define OFF_SCM  (OFF_RP + (size_t)32 * 76)
#define OFF_SHM  (OFF_SCM + (size_t)MM * OM)
#define OFF_PW   (OFF_SHM + (size_t)MM * OM)              // KSPLIT*2048*38
#define OFF_LP   (OFF_PW + (size_t)KSPLIT * BATCH * ORR)  // 512*16*40

// Branch-free inline tanh: no OCML call, ~6 VALU instrs, |err| ~1e-6.
__device__ __forceinline__ float tanh_fast(float x) {
  float ax = fabsf(x);
  float e  = __expf(-2.0f * ax);
  float r  = __fdividef(1.0f - e, 1.0f + e);
  return copysignf(r, x);
}

// fp32 -> bf16 bits, round-to-nearest-even, branch-free.
__device__ __forceinline__ unsigned short f2bf(float f) {
  unsigned u = __builtin_bit_cast(unsigned, f);
  return (unsigned short)((u + 0x7FFFu + ((u >> 16) & 1u)) >> 16);
}
__device__ __forceinline__ float bf2f(unsigned short u) {
  return __builtin_bit_cast(float, ((unsigned)u) << 16);
}

typedef __attribute__((ext_vector_type(8))) short short8v;   // 8 bf16 = 4 VGPR
typedef __attribute__((ext_vector_type(4))) float f32x4;

// ---------------- leaf: barrier-free prologue (B-frags direct from global) --
// r17-r24: leaf invariant 75-82us across every lever (occupancy, LDS instrs,
// MFMA, store shape, MLP) with nothing saturated -> stall-bound. Last
// untouched structure: the block prologue (W global load -> LDS stage ->
// barrier) serializing all 4 waves, x8192 blocks. This round: lane builds its
// B-frags DIRECTLY from global W (L2-hot: 1.3 MB total, 16 blocks share each
// s-slice); bias read as scalars. Deletes Wl/bl LDS + the first barrier.
__global__ __launch_bounds__(256) void k_leaf(
    const float* __restrict__ x, const float* __restrict__ W,
    const float* __restrict__ bias, float* __restrict__ child,
    float* __restrict__ lp)
{
  const int chunk = blockIdx.x;       // 0..15 (128 rows each)
  const int s = blockIdx.y;           // 0..511
  const int t = threadIdx.x;          // 0..255
  const int w = t >> 6, l = t & 63;
  const int col = l & 15;
  const int kb = (l >> 4) * 8;

  __shared__ float hb[OL * 132];            // 10560 B
  __shared__ float red[4][2 * OL];          // 640 B

  // issue BOTH tiles' x loads up-front
  const int row0 = chunk * 128 + 0 * 64 + w * 16 + col;
  const int row1 = chunk * 128 + 1 * 64 + w * 16 + col;
  const float4* xr0 = (const float4*)(x + ((size_t)s * BATCH + row0) * GL + kb);
  const float4* xr1 = (const float4*)(x + ((size_t)s * BATCH + row1) * GL + kb);
  float4 v00 = xr0[0];
  float4 v01 = xr0[1];
  float4 v10 = xr1[0];
  float4 v11 = xr1[1];

  // B fragments direct from global (r17/r18-verified layout)
  const float* Ws = W + (size_t)s * GL * OL;
  short8v b0, b1;
#pragma unroll
  for (int j = 0; j < 8; j++) {
    const int k = kb + j;
    b0[j] = (short)f2bf(Ws[k * OL + col]);
    b1[j] = (col < 4) ? (short)f2bf(Ws[k * OL + 16 + col]) : (short)0;
  }
  const float blv0 = bias[s * OL + col];
  const float blv1 = (col < 4) ? bias[s * OL + 16 + col] : 0.f;

  float sum0 = 0.f, ssq0 = 0.f, sum1 = 0.f, ssq1 = 0.f;
  const f32x4 zero = {0.f, 0.f, 0.f, 0.f};

  short8v a0, a1;
  a0[0] = (short)f2bf(v00.x); a0[1] = (short)f2bf(v00.y);
  a0[2] = (short)f2bf(v00.z); a0[3] = (short)f2bf(v00.w);
  a0[4] = (short)f2bf(v01.x); a0[5] = (short)f2bf(v01.y);
  a0[6] = (short)f2bf(v01.z); a0[7] = (short)f2bf(v01.w);
  a1[0] = (short)f2bf(v10.x); a1[1] = (short)f2bf(v10.y);
  a1[2] = (short)f2bf(v10.z); a1[3] = (short)f2bf(v10.w);
  a1[4] = (short)f2bf(v11.x); a1[5] = (short)f2bf(v11.y);
  a1[6] = (short)f2bf(v11.z); a1[7] = (short)f2bf(v11.w);

#pragma unroll
  for (int T = 0; T < 2; T++) {
    const int tl = T * 64 + w * 16;
    short8v a = (T == 0) ? a0 : a1;

    f32x4 d0 = __builtin_amdgcn_mfma_f32_16x16x32_bf16(a, b0, zero, 0, 0, 0);
    f32x4 d1 = __builtin_amdgcn_mfma_f32_16x16x32_bf16(a, b1, zero, 0, 0, 0);

    const int rowloc = tl + (l >> 4) * 4;
    float4 o0;
    o0.x = tanh_fast(d0[0] + blv0); o0.y = tanh_fast(d0[1] + blv0);
    o0.z = tanh_fast(d0[2] + blv0); o0.w = tanh_fast(d0[3] + blv0);
    sum0 += o0.x + o0.y + o0.z + o0.w;
    ssq0 = fmaf(o0.x, o0.x, fmaf(o0.y, o0.y, fmaf(o0.z, o0.z, fmaf(o0.w, o0.w, ssq0))));
    *(float4*)&hb[col * 132 + rowloc] = o0;
    if (col < 4) {
      float4 o1;
      o1.x = tanh_fast(d1[0] + blv1); o1.y = tanh_fast(d1[1] + blv1);
      o1.z = tanh_fast(d1[2] + blv1); o1.w = tanh_fast(d1[3] + blv1);
      sum1 += o1.x + o1.y + o1.z + o1.w;
      ssq1 = fmaf(o1.x, o1.x, fmaf(o1.y, o1.y, fmaf(o1.z, o1.z, fmaf(o1.w, o1.w, ssq1))));
      *(float4*)&hb[(16 + col) * 132 + rowloc] = o1;
    }
  }
  __syncthreads();

  // cooperative coalesced store: 20 planes x 128 floats = 640 float4
#pragma unroll
  for (int j = 0; j < 3; j++) {
    const int f = t + j * 256;               // 0..767
    if (f < 640) {
      const int plane = f >> 5, q = (f & 31) * 4;
      float4 v = *(const float4*)&hb[plane * 132 + q];
      *(float4*)&child[((size_t)s * OL + plane) * BATCH + chunk * 128 + q] = v;
    }
  }

  // ---- block BN partial sums ----
  sum0 += __shfl_xor(sum0, 16); sum0 += __shfl_xor(sum0, 32);
  ssq0 += __shfl_xor(ssq0, 16); ssq0 += __shfl_xor(ssq0, 32);
  sum1 += __shfl_xor(sum1, 16); sum1 += __shfl_xor(sum1, 32);
  ssq1 += __shfl_xor(ssq1, 16); ssq1 += __shfl_xor(ssq1, 32);
  if (l < 16) { red[w][l] = sum0; red[w][OL + l] = ssq0; }
  if (l < 4)  { red[w][16 + l] = sum1; red[w][OL + 16 + l] = ssq1; }
  __syncthreads();
  if (t < 2 * OL) {
    float v = red[0][t] + red[1][t] + red[2][t] + red[3][t];
    lp[((size_t)s * 16 + chunk) * (2 * OL) + t] = v;
  }
}

// ---------------- leaf BN affine finalize (tiny) ----------------------------
__global__ __launch_bounds__(256) void k_leafstats(
    const float* __restrict__ lp, const float* __restrict__ g,
    const float* __restrict__ be,
    float* __restrict__ scL, float* __restrict__ shL)
{
  const int e = blockIdx.x * 256 + threadIdx.x;   // 0..10239
  if (e >= SS * OL) return;
  const int s = e / OL, o = e % OL;
  float s1 = 0.f, s2 = 0.f;
#pragma unroll
  for (int c = 0; c < 16; c++) {
    s1 += lp[((size_t)s * 16 + c) * (2 * OL) + o];
    s2 += lp[((size_t)s * 16 + c) * (2 * OL) + OL + o];
  }
  float mean = s1 * (1.f / BATCH);
  float var  = s2 * (1.f / BATCH) - mean * mean;
  float rs = rsqrtf(var + EPSBN);
  float sc = g[e] * rs;
  scL[e] = sc;
  shL[e] = be[e] - mean * sc;
}

// ---------------- mid: bf16 MFMA GEMM, K=384 (r22-proven) -------------------
__global__ __launch_bounds__(256) void k_mid(
    const float* __restrict__ xg, const float* __restrict__ child,
    const float* __restrict__ scL, const float* __restrict__ shL,
    const float* __restrict__ W, const float* __restrict__ bias,
    float* __restrict__ hm, float* __restrict__ mp)
{
  const int chunk = blockIdx.x;   // 0..31 (64 rows each)
  const int m = blockIdx.y;       // 0..31
  const int t = threadIdx.x;      // 0..255
  const int w = t >> 6, l = t & 63;
  const int col = l & 15;
  const int kb = (l >> 4) * 8;

  __shared__ short bfr[12 * 2 * 64 * 8];   // 24576 B, fragment-ordered B'
  __shared__ float ovl[1360];              // phase1 scs|shs|part, phase2 hb[20][68]
  __shared__ float red[4][2 * OM];         // 640 B
  __shared__ float bias2[OM];              // 80 B

  float* scs = ovl;            // [320]
  float* shs = ovl + 320;      // [320]
  float* part = ovl + 640;     // [160]
  float* hb = ovl;             // phase 2: [20][68]

  const float* Wm = W + (size_t)m * IMID * OM;

  if (t < 80)       ((float4*)scs)[t]      = ((const float4*)(scL + m * CC * OL))[t];
  else if (t < 160) ((float4*)shs)[t - 80] = ((const float4*)(shL + m * CC * OL))[t - 80];
  __syncthreads();

#pragma unroll 1
  for (int i = 0; i < 48; i++) {
    const int e = t + i * 256;             // 0..12287
    const int kt = e >> 10;
    const int ct = (e >> 9) & 1;
    const int ll = (e >> 3) & 63;
    const int j = e & 7;
    const int k = kt * 32 + (ll >> 4) * 8 + j;
    const int n = ct * 16 + (ll & 15);
    float val = 0.f;
    if (n < OM) {
      float wv = Wm[k * OM + n];
      val = (k < GM) ? wv : scs[k - GM] * wv;
    }
    bfr[e] = (short)f2bf(val);
  }
  if (t < 160) {
    const int n = t >> 3, p = t & 7;
    const int fb = p * 40;
    float sacc = 0.f;
#pragma unroll 1
    for (int f = 0; f < 40; f++)
      sacc = fmaf(shs[fb + f], Wm[(GM + fb + f) * OM + n], sacc);
    part[t] = sacc;
  }
  __syncthreads();
  if (t < OM) {
    float sb = bias[m * OM + t];
#pragma unroll
    for (int p = 0; p < 8; p++) sb += part[t * 8 + p];
    bias2[t] = sb;
  }
  __syncthreads();

  const int row = chunk * 64 + w * 16 + col;
  f32x4 acc0 = {0.f, 0.f, 0.f, 0.f};
  f32x4 acc1 = {0.f, 0.f, 0.f, 0.f};

#pragma unroll
  for (int kt = 0; kt < 2; kt++) {
    const float4* gp = (const float4*)(xg + ((size_t)m * BATCH + row) * GM + kt * 32 + kb);
    float4 v0 = gp[0], v1 = gp[1];
    short8v a;
    a[0] = (short)f2bf(v0.x); a[1] = (short)f2bf(v0.y);
    a[2] = (short)f2bf(v0.z); a[3] = (short)f2bf(v0.w);
    a[4] = (short)f2bf(v1.x); a[5] = (short)f2bf(v1.y);
    a[6] = (short)f2bf(v1.z); a[7] = (short)f2bf(v1.w);
    short8v bf0 = *(const short8v*)&bfr[kt * 1024 + l * 8];
    short8v bf1 = *(const short8v*)&bfr[kt * 1024 + 512 + l * 8];
    acc0 = __builtin_amdgcn_mfma_f32_16x16x32_bf16(a, bf0, acc0, 0, 0, 0);
    acc1 = __builtin_amdgcn_mfma_f32_16x16x32_bf16(a, bf1, acc1, 0, 0, 0);
  }
#pragma unroll 1
  for (int kt = 2; kt < 12; kt++) {
    const float* cp = child + ((size_t)m * (CC * OL) + (kt - 2) * 32 + kb) * BATCH + row;
    short8v ah, al;
#pragma unroll
    for (int j = 0; j < 8; j++) {
      float v = cp[(size_t)j * BATCH];
      unsigned short hi = f2bf(v);
      ah[j] = (short)hi;
      al[j] = (short)f2bf(v - bf2f(hi));
    }
    short8v bf0 = *(const short8v*)&bfr[kt * 1024 + l * 8];
    short8v bf1 = *(const short8v*)&bfr[kt * 1024 + 512 + l * 8];
    acc0 = __builtin_amdgcn_mfma_f32_16x16x32_bf16(ah, bf0, acc0, 0, 0, 0);
    acc0 = __builtin_amdgcn_mfma_f32_16x16x32_bf16(al, bf0, acc0, 0, 0, 0);
    acc1 = __builtin_amdgcn_mfma_f32_16x16x32_bf16(ah, bf1, acc1, 0, 0, 0);
    acc1 = __builtin_amdgcn_mfma_f32_16x16x32_bf16(al, bf1, acc1, 0, 0, 0);
  }

  const float bv0 = bias2[col];
  const float bv1 = (col < 4) ? bias2[16 + col] : 0.f;
  const int rowloc = w * 16 + (l >> 4) * 4;
  float sum0, ssq0, sum1 = 0.f, ssq1 = 0.f;
  {
    float4 o0;
    o0.x = tanh_fast(acc0[0] + bv0); o0.y = tanh_fast(acc0[1] + bv0);
    o0.z = tanh_fast(acc0[2] + bv0); o0.w = tanh_fast(acc0[3] + bv0);
    sum0 = o0.x + o0.y + o0.z + o0.w;
    ssq0 = fmaf(o0.x, o0.x, fmaf(o0.y, o0.y, fmaf(o0.z, o0.z, o0.w * o0.w)));
    *(float4*)&hb[col * 68 + rowloc] = o0;
    if (col < 4) {
      float4 o1;
      o1.x = tanh_fast(acc1[0] + bv1); o1.y = tanh_fast(acc1[1] + bv1);
      o1.z = tanh_fast(acc1[2] + bv1); o1.w = tanh_fast(acc1[3] + bv1);
      sum1 = o1.x + o1.y + o1.z + o1.w;
      ssq1 = fmaf(o1.x, o1.x, fmaf(o1.y, o1.y, fmaf(o1.z, o1.z, o1.w * o1.w)));
      *(float4*)&hb[(16 + col) * 68 + rowloc] = o1;
    }
  }
  __syncthreads();

  {
    const int f = t;                        // 0..255
    const int plane = f >> 4, q = (f & 15) * 4;
    float4 v = *(const float4*)&hb[plane * 68 + q];
    *(float4*)&hm[((size_t)m * OM + plane) * BATCH + chunk * 64 + q] = v;
  }
  if (t < 64) {
    const int f = t + 256;                  // 256..319
    const int plane = f >> 4, q = (f & 15) * 4;
    float4 v = *(const float4*)&hb[plane * 68 + q];
    *(float4*)&hm[((size_t)m * OM + plane) * BATCH + chunk * 64 + q] = v;
  }

  sum0 += __shfl_xor(sum0, 16); sum0 += __shfl_xor(sum0, 32);
  ssq0 += __shfl_xor(ssq0, 16); ssq0 += __shfl_xor(ssq0, 32);
  sum1 += __shfl_xor(sum1, 16); sum1 += __shfl_xor(sum1, 32);
  ssq1 += __shfl_xor(ssq1, 16); ssq1 += __shfl_xor(ssq1, 32);
  if (l < 16) { red[w][l] = sum0; red[w][OM + l] = ssq0; }
  if (l < 4)  { red[w][16 + l] = sum1; red[w][OM + 16 + l] = ssq1; }
  __syncthreads();
  if (t < 2 * OM) {
    float v = red[0][t] + red[1][t] + red[2][t] + red[3][t];
    mp[((size_t)m * 32 + chunk) * (2 * OM) + t] = v;
  }
}

// ---------------- mid BN affine finalize (tiny) -----------------------------
__global__ __launch_bounds__(256) void k_midstats(
    const float* __restrict__ mp, const float* __restrict__ g_mid,
    const float* __restrict__ be_mid,
    float* __restrict__ scm, float* __restrict__ shm)
{
  const int e = blockIdx.x * 256 + threadIdx.x;
  if (e >= MM * OM) return;
  const int m = e / OM, o = e % OM;
  float s1 = 0.f, s2 = 0.f;
  for (int c = 0; c < 32; c++) {
    s1 += mp[((size_t)m * 32 + c) * (2 * OM) + o];
    s2 += mp[((size_t)m * 32 + c) * (2 * OM) + OM + o];
  }
  float mean = s1 * (1.f / BATCH);
  float var  = s2 * (1.f / BATCH) - mean * mean;
  float r = rsqrtf(var + EPSBN);
  float sc = g_mid[e] * r;
  scm[e] = sc;
  shm[e] = be_mid[e] - mean * sc;
}

// ---------------- root partial GEMM: K split 16 ways ------------------------
__global__ __launch_bounds__(256, 2) void k_root_partial(
    const float* __restrict__ xr, const float* __restrict__ hm,
    const float* __restrict__ scm, const float* __restrict__ shm,
    const float* __restrict__ W, float* __restrict__ pw)
{
  const int rc = blockIdx.x;      // 0..31
  const int kc = blockIdx.y;      // 0..15
  const int t = threadIdx.x;
  const int w = t >> 6, lane = t & 63;
  const int ob = w * 10;
  const bool full = (w < 3);
  const int b = rc * 64 + lane;
  const int k0 = kc * KCH;

  __shared__ float Wl[KCH * ORR];
  __shared__ float scs[KCH], shs[KCH];

  for (int i = t; i < KCH * ORR; i += 256)
    Wl[i] = W[(size_t)k0 * ORR + i];
  if (t < KCH) {
    const int mi = k0 + t - GR;
    const bool v = (mi >= 0);
    scs[t] = v ? scm[mi] : 0.f;
    shs[t] = v ? shm[mi] : 0.f;
  }
  __syncthreads();

  float acc[10];
#pragma unroll
  for (int j = 0; j < 10; j++) acc[j] = 0.f;

#define FMA10(xs, kk) do { \
    const float2* wr = (const float2*)(Wl + (size_t)(kk) * ORR + ob); \
    float2 w0 = wr[0], w1 = wr[1], w2 = wr[2], w3 = wr[3]; \
    float2 w4 = full ? wr[4] : make_float2(0.f, 0.f); \
    acc[0]=fmaf(xs,w0.x,acc[0]); acc[1]=fmaf(xs,w0.y,acc[1]); \
    acc[2]=fmaf(xs,w1.x,acc[2]); acc[3]=fmaf(xs,w1.y,acc[3]); \
    acc[4]=fmaf(xs,w2.x,acc[4]); acc[5]=fmaf(xs,w2.y,acc[5]); \
    acc[6]=fmaf(xs,w3.x,acc[6]); acc[7]=fmaf(xs,w3.y,acc[7]); \
    acc[8]=fmaf(xs,w4.x,acc[8]); acc[9]=fmaf(xs,w4.y,acc[9]); \
  } while (0)

#pragma unroll 2
  for (int g = 0; g < KCH / 4; g++) {
    const int k = k0 + g * 4;
    float xa[4];
    if (k < GR) {
      float4 xv = *(const float4*)(xr + (size_t)b * GR + k);
      xa[0] = xv.x; xa[1] = xv.y; xa[2] = xv.z; xa[3] = xv.w;
    } else {
      const int mi = k - GR;
      const float* hp = hm + (size_t)mi * BATCH + b;
      const int lk = g * 4;
#pragma unroll
      for (int j = 0; j < 4; j++)
        xa[j] = fmaf(hp[(size_t)j * BATCH], scs[lk + j], shs[lk + j]);
    }
#pragma unroll
    for (int j = 0; j < 4; j++) FMA10(xa[j], g * 4 + j);
  }
#undef FMA10

  const size_t base = ((size_t)kc * BATCH + b) * ORR + ob;
#pragma unroll
  for (int j = 0; j < 10; j++)
    if (j < 8 || full) pw[base + j] = acc[j];
}

// ---------------- root finalize: sum partials + bias + tanh + BN partials ---
__global__ __launch_bounds__(256) void k_rootfinal(
    const float* __restrict__ pw, const float* __restrict__ bias,
    float* __restrict__ hr, float* __restrict__ rp)
{
  const int blk = blockIdx.x;     // 0..31
  const int t = threadIdx.x;
  const int w = t >> 6, lane = t & 63;
  const int ob = w * 10;
  const bool full = (w < 3);
  const int b = blk * 64 + lane;

  float acc[10];
#pragma unroll
  for (int j = 0; j < 10; j++) acc[j] = 0.f;

#pragma unroll 1
  for (int kc = 0; kc < KSPLIT; kc++) {
    const size_t base = ((size_t)kc * BATCH + b) * ORR + ob;
#pragma unroll
    for (int j = 0; j < 10; j++)
      if (j < 8 || full) acc[j] += pw[base + j];
  }

#pragma unroll
  for (int j = 0; j < 10; j++) {
    float bj = (j < 8 || full) ? bias[ob + j] : 0.f;
    acc[j] = tanh_fast(acc[j] + bj);
  }

#pragma unroll
  for (int j = 0; j < 10; j++) {
    float s1 = acc[j], s2 = acc[j] * acc[j];
#pragma unroll
    for (int d = 32; d >= 1; d >>= 1) { s1 += __shfl_xor(s1, d); s2 += __shfl_xor(s2, d); }
    if (lane == 0 && (j < 8 || full)) {
      rp[blk * 76 + ob + j] = s1;
      rp[blk * 76 + ORR + ob + j] = s2;
    }
  }
#pragma unroll
  for (int j = 0; j < 10; j++)
    if (j < 8 || full) hr[(size_t)b * ORR + ob + j] = acc[j];
}

// ---------------- root BN finalize -> output --------------------------------
__global__ __launch_bounds__(256) void k_rootnorm(
    const float* __restrict__ hr, const float* __restrict__ rp,
    const float* __restrict__ g, const float* __restrict__ be,
    float* __restrict__ out)
{
  __shared__ float sc[ORR], sh[ORR];
  const int t = threadIdx.x;
  if (t < ORR) {
    float s1 = 0.f, s2 = 0.f;
    for (int blk = 0; blk < 32; blk++) {
      s1 += rp[blk * 76 + t];
      s2 += rp[blk * 76 + ORR + t];
    }
    float mean = s1 * (1.f / BATCH);
    float var  = s2 * (1.f / BATCH) - mean * mean;
    float r = rsqrtf(var + EPSBN);
    float scv = g[t] * r;
    sc[t] = scv;
    sh[t] = be[t] - mean * scv;
  }
  __syncthreads();
  const int idx = blockIdx.x * 256 + t;   // 304*256 = 77824 exactly
  const int o = idx % ORR;
  out[idx] = hr[idx] * sc[o] + sh[o];
}

extern "C" void kernel_launch(void* const* d_in, const int* in_sizes, int n_in,
                              void* d_out, int out_size, void* d_ws, size_t ws_size,
                              hipStream_t stream) {
  (void)in_sizes; (void)n_in; (void)out_size; (void)ws_size;
  const float* x_leaf  = (const float*)d_in[0];
  const float* x_mid   = (const float*)d_in[1];
  const float* x_root  = (const float*)d_in[2];
  const float* W_leaf  = (const float*)d_in[3];
  const float* b_leaf  = (const float*)d_in[4];
  const float* g_leaf  = (const float*)d_in[5];
  const float* be_leaf = (const float*)d_in[6];
  const float* W_mid   = (const float*)d_in[7];
  const float* b_mid   = (const float*)d_in[8];
  const float* g_mid   = (const float*)d_in[9];
  const float* be_mid  = (const float*)d_in[10];
  const float* W_root  = (const float*)d_in[11];
  const float* b_root  = (const float*)d_in[12];
  const float* g_root  = (const float*)d_in[13];
  const float* be_root = (const float*)d_in[14];
  float* out = (float*)d_out;
  float* ws  = (float*)d_ws;

  float* child = ws;
  float* scL   = ws + OFF_SCL;
  float* shL   = ws + OFF_SHL;
  float* hm    = ws + OFF_HM;
  float* mp    = ws + OFF_MP;
  float* hr    = ws + OFF_HR;
  float* rp    = ws + OFF_RP;
  float* scm   = ws + OFF_SCM;
  float* shm   = ws + OFF_SHM;
  float* pw    = ws + OFF_PW;
  float* lp    = ws + OFF_LP;

  k_leaf<<<dim3(16, SS), 256, 0, stream>>>(x_leaf, W_leaf, b_leaf, child, lp);
  k_leafstats<<<40, 256, 0, stream>>>(lp, g_leaf, be_leaf, scL, shL);
  k_mid<<<dim3(32, MM), 256, 0, stream>>>(x_mid, child, scL, shL, W_mid, b_mid,
                                          hm, mp);
  k_midstats<<<3, 256, 0, stream>>>(mp, g_mid, be_mid, scm, shm);
  k_root_partial<<<dim3(32, KSPLIT), 256, 0, stream>>>(x_root, hm, scm, shm,
                                                       W_root, pw);
  k_rootfinal<<<32, 256, 0, stream>>>(pw, b_root, hr, rp);
  k_rootnorm<<<304, 256, 0, stream>>>(hr, rp, g_root, be_root, out);
}

// Round 26
// 106.761 us; speedup vs baseline: 1.0969x; 1.0969x over previous
//
#include <hip/hip_runtime.h>
#include <hip/hip_bf16.h>

#define SS 512
#define BATCH 2048
#define GL 32
#define OL 20
#define MM 32
#define CC 16
#define GM 64
#define OM 20
#define GR 128
#define ORR 38
#define IMID 384
#define IROOT 768
#define EPSBN 1e-5f

#define KSPLIT 16
#define KCH 48            // 768 / 16

// ---- workspace layout (floats; child fp32) ----
#define SZ_CHILD ((size_t)SS * OL * BATCH)
#define OFF_SCL  (SZ_CHILD)
#define OFF_SHL  (OFF_SCL + (size_t)SS * OL)
#define OFF_HM   (OFF_SHL + (size_t)SS * OL)
#define OFF_MP   (OFF_HM + (size_t)MM * OM * BATCH)
#define OFF_HR   (OFF_MP + (size_t)MM * 32 * 2 * OM)
#define OFF_RP   (OFF_HR + (size_t)BATCH * ORR)
#define OFF_SCM  (OFF_RP + (size_t)32 * 76)
#define OFF_SHM  (OFF_SCM + (size_t)MM * OM)
#define OFF_PW   (OFF_SHM + (size_t)MM * OM)              // KSPLIT*2048*38
#define OFF_LP   (OFF_PW + (size_t)KSPLIT * BATCH * ORR)  // 512*8*40

// Branch-free inline tanh: no OCML call, ~6 VALU instrs, |err| ~1e-6.
__device__ __forceinline__ float tanh_fast(float x) {
  float ax = fabsf(x);
  float e  = __expf(-2.0f * ax);
  float r  = __fdividef(1.0f - e, 1.0f + e);
  return copysignf(r, x);
}

// fp32 -> bf16 bits, round-to-nearest-even, branch-free.
__device__ __forceinline__ unsigned short f2bf(float f) {
  unsigned u = __builtin_bit_cast(unsigned, f);
  return (unsigned short)((u + 0x7FFFu + ((u >> 16) & 1u)) >> 16);
}
__device__ __forceinline__ float bf2f(unsigned short u) {
  return __builtin_bit_cast(float, ((unsigned)u) << 16);
}

typedef __attribute__((ext_vector_type(8))) short short8v;   // 8 bf16 = 4 VGPR
typedef __attribute__((ext_vector_type(4))) float f32x4;

// ---------------- leaf: r22-best MFMA core (measured 106.9us total) ---------
// Session ledger: leaf pinned 75-83us across occupancy 33-81%, LDS 3.5-24KB,
// VALU->MFMA, scattered->coalesced stores, MLP hoisting, prologue removal.
// This is the best-measured configuration (r22): 256-row slabs, grid (8,SS).
__global__ __launch_bounds__(256) void k_leaf(
    const float* __restrict__ x, const float* __restrict__ W,
    const float* __restrict__ bias, float* __restrict__ child,
    float* __restrict__ lp)
{
  const int chunk = blockIdx.x;       // 0..7 (256 rows each)
  const int s = blockIdx.y;           // 0..511
  const int t = threadIdx.x;          // 0..255
  const int w = t >> 6, l = t & 63;
  const int col = l & 15;
  const int kb = (l >> 4) * 8;

  __shared__ float hb[OL * 260];            // 20800 B
  __shared__ float Wl[GL * OL];             // 2560 B
  __shared__ float bl[OL];
  __shared__ float red[4][2 * OL];          // 640 B

  if (t < GL * OL / 4)
    ((float4*)Wl)[t] = ((const float4*)(W + (size_t)s * GL * OL))[t];
  else if (t >= 160 && t < 165)
    ((float4*)bl)[t - 160] = ((const float4*)(bias + s * OL))[t - 160];
  __syncthreads();

  short8v b0, b1;
#pragma unroll
  for (int j = 0; j < 8; j++) {
    const int k = kb + j;
    b0[j] = (short)f2bf(Wl[k * OL + col]);
    b1[j] = (col < 4) ? (short)f2bf(Wl[k * OL + 16 + col]) : (short)0;
  }
  const float blv0 = bl[col];
  const float blv1 = (col < 4) ? bl[16 + col] : 0.f;

  float sum0 = 0.f, ssq0 = 0.f, sum1 = 0.f, ssq1 = 0.f;
  const f32x4 zero = {0.f, 0.f, 0.f, 0.f};

#pragma unroll
  for (int T = 0; T < 4; T++) {
    const int tl = T * 64 + w * 16;
    const int row_g = chunk * 256 + tl + col;
    const float4* xr = (const float4*)(x + ((size_t)s * BATCH + row_g) * GL + kb);
    float4 v0 = xr[0], v1 = xr[1];
    short8v a;
    a[0] = (short)f2bf(v0.x); a[1] = (short)f2bf(v0.y);
    a[2] = (short)f2bf(v0.z); a[3] = (short)f2bf(v0.w);
    a[4] = (short)f2bf(v1.x); a[5] = (short)f2bf(v1.y);
    a[6] = (short)f2bf(v1.z); a[7] = (short)f2bf(v1.w);

    f32x4 d0 = __builtin_amdgcn_mfma_f32_16x16x32_bf16(a, b0, zero, 0, 0, 0);
    f32x4 d1 = __builtin_amdgcn_mfma_f32_16x16x32_bf16(a, b1, zero, 0, 0, 0);

    const int rowloc = tl + (l >> 4) * 4;
    float4 o0;
    o0.x = tanh_fast(d0[0] + blv0); o0.y = tanh_fast(d0[1] + blv0);
    o0.z = tanh_fast(d0[2] + blv0); o0.w = tanh_fast(d0[3] + blv0);
    sum0 += o0.x + o0.y + o0.z + o0.w;
    ssq0 = fmaf(o0.x, o0.x, fmaf(o0.y, o0.y, fmaf(o0.z, o0.z, fmaf(o0.w, o0.w, ssq0))));
    *(float4*)&hb[col * 260 + rowloc] = o0;
    if (col < 4) {
      float4 o1;
      o1.x = tanh_fast(d1[0] + blv1); o1.y = tanh_fast(d1[1] + blv1);
      o1.z = tanh_fast(d1[2] + blv1); o1.w = tanh_fast(d1[3] + blv1);
      sum1 += o1.x + o1.y + o1.z + o1.w;
      ssq1 = fmaf(o1.x, o1.x, fmaf(o1.y, o1.y, fmaf(o1.z, o1.z, fmaf(o1.w, o1.w, ssq1))));
      *(float4*)&hb[(16 + col) * 260 + rowloc] = o1;
    }
  }
  __syncthreads();

#pragma unroll
  for (int j = 0; j < 5; j++) {
    const int f = t + j * 256;               // 0..1279
    const int plane = f >> 6, q = (f & 63) * 4;
    float4 v = *(const float4*)&hb[plane * 260 + q];
    *(float4*)&child[((size_t)s * OL + plane) * BATCH + chunk * 256 + q] = v;
  }

  sum0 += __shfl_xor(sum0, 16); sum0 += __shfl_xor(sum0, 32);
  ssq0 += __shfl_xor(ssq0, 16); ssq0 += __shfl_xor(ssq0, 32);
  sum1 += __shfl_xor(sum1, 16); sum1 += __shfl_xor(sum1, 32);
  ssq1 += __shfl_xor(ssq1, 16); ssq1 += __shfl_xor(ssq1, 32);
  if (l < 16) { red[w][l] = sum0; red[w][OL + l] = ssq0; }
  if (l < 4)  { red[w][16 + l] = sum1; red[w][OL + 16 + l] = ssq1; }
  __syncthreads();
  if (t < 2 * OL) {
    float v = red[0][t] + red[1][t] + red[2][t] + red[3][t];
    lp[((size_t)s * 8 + chunk) * (2 * OL) + t] = v;
  }
}

// ---------------- leaf BN affine finalize (tiny) ----------------------------
__global__ __launch_bounds__(256) void k_leafstats(
    const float* __restrict__ lp, const float* __restrict__ g,
    const float* __restrict__ be,
    float* __restrict__ scL, float* __restrict__ shL)
{
  const int e = blockIdx.x * 256 + threadIdx.x;   // 0..10239
  if (e >= SS * OL) return;
  const int s = e / OL, o = e % OL;
  float s1 = 0.f, s2 = 0.f;
#pragma unroll
  for (int c = 0; c < 8; c++) {
    s1 += lp[((size_t)s * 8 + c) * (2 * OL) + o];
    s2 += lp[((size_t)s * 8 + c) * (2 * OL) + OL + o];
  }
  float mean = s1 * (1.f / BATCH);
  float var  = s2 * (1.f / BATCH) - mean * mean;
  float rs = rsqrtf(var + EPSBN);
  float sc = g[e] * rs;
  scL[e] = sc;
  shL[e] = be[e] - mean * sc;
}

// ---------------- mid: bf16 MFMA GEMM, K=384 (r22-proven) -------------------
__global__ __launch_bounds__(256) void k_mid(
    const float* __restrict__ xg, const float* __restrict__ child,
    const float* __restrict__ scL, const float* __restrict__ shL,
    const float* __restrict__ W, const float* __restrict__ bias,
    float* __restrict__ hm, float* __restrict__ mp)
{
  const int chunk = blockIdx.x;   // 0..31 (64 rows each)
  const int m = blockIdx.y;       // 0..31
  const int t = threadIdx.x;      // 0..255
  const int w = t >> 6, l = t & 63;
  const int col = l & 15;
  const int kb = (l >> 4) * 8;

  __shared__ short bfr[12 * 2 * 64 * 8];   // 24576 B, fragment-ordered B'
  __shared__ float ovl[1360];              // phase1 scs|shs|part, phase2 hb[20][68]
  __shared__ float red[4][2 * OM];         // 640 B
  __shared__ float bias2[OM];              // 80 B

  float* scs = ovl;            // [320]
  float* shs = ovl + 320;      // [320]
  float* part = ovl + 640;     // [160]
  float* hb = ovl;             // phase 2: [20][68]

  const float* Wm = W + (size_t)m * IMID * OM;

  if (t < 80)       ((float4*)scs)[t]      = ((const float4*)(scL + m * CC * OL))[t];
  else if (t < 160) ((float4*)shs)[t - 80] = ((const float4*)(shL + m * CC * OL))[t - 80];
  __syncthreads();

#pragma unroll 1
  for (int i = 0; i < 48; i++) {
    const int e = t + i * 256;             // 0..12287
    const int kt = e >> 10;
    const int ct = (e >> 9) & 1;
    const int ll = (e >> 3) & 63;
    const int j = e & 7;
    const int k = kt * 32 + (ll >> 4) * 8 + j;
    const int n = ct * 16 + (ll & 15);
    float val = 0.f;
    if (n < OM) {
      float wv = Wm[k * OM + n];
      val = (k < GM) ? wv : scs[k - GM] * wv;
    }
    bfr[e] = (short)f2bf(val);
  }
  if (t < 160) {
    const int n = t >> 3, p = t & 7;
    const int fb = p * 40;
    float sacc = 0.f;
#pragma unroll 1
    for (int f = 0; f < 40; f++)
      sacc = fmaf(shs[fb + f], Wm[(GM + fb + f) * OM + n], sacc);
    part[t] = sacc;
  }
  __syncthreads();
  if (t < OM) {
    float sb = bias[m * OM + t];
#pragma unroll
    for (int p = 0; p < 8; p++) sb += part[t * 8 + p];
    bias2[t] = sb;
  }
  __syncthreads();

  const int row = chunk * 64 + w * 16 + col;
  f32x4 acc0 = {0.f, 0.f, 0.f, 0.f};
  f32x4 acc1 = {0.f, 0.f, 0.f, 0.f};

#pragma unroll
  for (int kt = 0; kt < 2; kt++) {
    const float4* gp = (const float4*)(xg + ((size_t)m * BATCH + row) * GM + kt * 32 + kb);
    float4 v0 = gp[0], v1 = gp[1];
    short8v a;
    a[0] = (short)f2bf(v0.x); a[1] = (short)f2bf(v0.y);
    a[2] = (short)f2bf(v0.z); a[3] = (short)f2bf(v0.w);
    a[4] = (short)f2bf(v1.x); a[5] = (short)f2bf(v1.y);
    a[6] = (short)f2bf(v1.z); a[7] = (short)f2bf(v1.w);
    short8v bf0 = *(const short8v*)&bfr[kt * 1024 + l * 8];
    short8v bf1 = *(const short8v*)&bfr[kt * 1024 + 512 + l * 8];
    acc0 = __builtin_amdgcn_mfma_f32_16x16x32_bf16(a, bf0, acc0, 0, 0, 0);
    acc1 = __builtin_amdgcn_mfma_f32_16x16x32_bf16(a, bf1, acc1, 0, 0, 0);
  }
#pragma unroll 1
  for (int kt = 2; kt < 12; kt++) {
    const float* cp = child + ((size_t)m * (CC * OL) + (kt - 2) * 32 + kb) * BATCH + row;
    short8v ah, al;
#pragma unroll
    for (int j = 0; j < 8; j++) {
      float v = cp[(size_t)j * BATCH];
      unsigned short hi = f2bf(v);
      ah[j] = (short)hi;
      al[j] = (short)f2bf(v - bf2f(hi));
    }
    short8v bf0 = *(const short8v*)&bfr[kt * 1024 + l * 8];
    short8v bf1 = *(const short8v*)&bfr[kt * 1024 + 512 + l * 8];
    acc0 = __builtin_amdgcn_mfma_f32_16x16x32_bf16(ah, bf0, acc0, 0, 0, 0);
    acc0 = __builtin_amdgcn_mfma_f32_16x16x32_bf16(al, bf0, acc0, 0, 0, 0);
    acc1 = __builtin_amdgcn_mfma_f32_16x16x32_bf16(ah, bf1, acc1, 0, 0, 0);
    acc1 = __builtin_amdgcn_mfma_f32_16x16x32_bf16(al, bf1, acc1, 0, 0, 0);
  }

  const float bv0 = bias2[col];
  const float bv1 = (col < 4) ? bias2[16 + col] : 0.f;
  const int rowloc = w * 16 + (l >> 4) * 4;
  float sum0, ssq0, sum1 = 0.f, ssq1 = 0.f;
  {
    float4 o0;
    o0.x = tanh_fast(acc0[0] + bv0); o0.y = tanh_fast(acc0[1] + bv0);
    o0.z = tanh_fast(acc0[2] + bv0); o0.w = tanh_fast(acc0[3] + bv0);
    sum0 = o0.x + o0.y + o0.z + o0.w;
    ssq0 = fmaf(o0.x, o0.x, fmaf(o0.y, o0.y, fmaf(o0.z, o0.z, o0.w * o0.w)));
    *(float4*)&hb[col * 68 + rowloc] = o0;
    if (col < 4) {
      float4 o1;
      o1.x = tanh_fast(acc1[0] + bv1); o1.y = tanh_fast(acc1[1] + bv1);
      o1.z = tanh_fast(acc1[2] + bv1); o1.w = tanh_fast(acc1[3] + bv1);
      sum1 = o1.x + o1.y + o1.z + o1.w;
      ssq1 = fmaf(o1.x, o1.x, fmaf(o1.y, o1.y, fmaf(o1.z, o1.z, o1.w * o1.w)));
      *(float4*)&hb[(16 + col) * 68 + rowloc] = o1;
    }
  }
  __syncthreads();

  {
    const int f = t;                        // 0..255
    const int plane = f >> 4, q = (f & 15) * 4;
    float4 v = *(const float4*)&hb[plane * 68 + q];
    *(float4*)&hm[((size_t)m * OM + plane) * BATCH + chunk * 64 + q] = v;
  }
  if (t < 64) {
    const int f = t + 256;                  // 256..319
    const int plane = f >> 4, q = (f & 15) * 4;
    float4 v = *(const float4*)&hb[plane * 68 + q];
    *(float4*)&hm[((size_t)m * OM + plane) * BATCH + chunk * 64 + q] = v;
  }

  sum0 += __shfl_xor(sum0, 16); sum0 += __shfl_xor(sum0, 32);
  ssq0 += __shfl_xor(ssq0, 16); ssq0 += __shfl_xor(ssq0, 32);
  sum1 += __shfl_xor(sum1, 16); sum1 += __shfl_xor(sum1, 32);
  ssq1 += __shfl_xor(ssq1, 16); ssq1 += __shfl_xor(ssq1, 32);
  if (l < 16) { red[w][l] = sum0; red[w][OM + l] = ssq0; }
  if (l < 4)  { red[w][16 + l] = sum1; red[w][OM + 16 + l] = ssq1; }
  __syncthreads();
  if (t < 2 * OM) {
    float v = red[0][t] + red[1][t] + red[2][t] + red[3][t];
    mp[((size_t)m * 32 + chunk) * (2 * OM) + t] = v;
  }
}

// ---------------- mid BN affine finalize (tiny) -----------------------------
__global__ __launch_bounds__(256) void k_midstats(
    const float* __restrict__ mp, const float* __restrict__ g_mid,
    const float* __restrict__ be_mid,
    float* __restrict__ scm, float* __restrict__ shm)
{
  const int e = blockIdx.x * 256 + threadIdx.x;
  if (e >= MM * OM) return;
  const int m = e / OM, o = e % OM;
  float s1 = 0.f, s2 = 0.f;
  for (int c = 0; c < 32; c++) {
    s1 += mp[((size_t)m * 32 + c) * (2 * OM) + o];
    s2 += mp[((size_t)m * 32 + c) * (2 * OM) + OM + o];
  }
  float mean = s1 * (1.f / BATCH);
  float var  = s2 * (1.f / BATCH) - mean * mean;
  float r = rsqrtf(var + EPSBN);
  float sc = g_mid[e] * r;
  scm[e] = sc;
  shm[e] = be_mid[e] - mean * sc;
}

// ---------------- root partial GEMM: K split 16 ways ------------------------
__global__ __launch_bounds__(256, 2) void k_root_partial(
    const float* __restrict__ xr, const float* __restrict__ hm,
    const float* __restrict__ scm, const float* __restrict__ shm,
    const float* __restrict__ W, float* __restrict__ pw)
{
  const int rc = blockIdx.x;      // 0..31
  const int kc = blockIdx.y;      // 0..15
  const int t = threadIdx.x;
  const int w = t >> 6, lane = t & 63;
  const int ob = w * 10;
  const bool full = (w < 3);
  const int b = rc * 64 + lane;
  const int k0 = kc * KCH;

  __shared__ float Wl[KCH * ORR];
  __shared__ float scs[KCH], shs[KCH];

  for (int i = t; i < KCH * ORR; i += 256)
    Wl[i] = W[(size_t)k0 * ORR + i];
  if (t < KCH) {
    const int mi = k0 + t - GR;
    const bool v = (mi >= 0);
    scs[t] = v ? scm[mi] : 0.f;
    shs[t] = v ? shm[mi] : 0.f;
  }
  __syncthreads();

  float acc[10];
#pragma unroll
  for (int j = 0; j < 10; j++) acc[j] = 0.f;

#define FMA10(xs, kk) do { \
    const float2* wr = (const float2*)(Wl + (size_t)(kk) * ORR + ob); \
    float2 w0 = wr[0], w1 = wr[1], w2 = wr[2], w3 = wr[3]; \
    float2 w4 = full ? wr[4] : make_float2(0.f, 0.f); \
    acc[0]=fmaf(xs,w0.x,acc[0]); acc[1]=fmaf(xs,w0.y,acc[1]); \
    acc[2]=fmaf(xs,w1.x,acc[2]); acc[3]=fmaf(xs,w1.y,acc[3]); \
    acc[4]=fmaf(xs,w2.x,acc[4]); acc[5]=fmaf(xs,w2.y,acc[5]); \
    acc[6]=fmaf(xs,w3.x,acc[6]); acc[7]=fmaf(xs,w3.y,acc[7]); \
    acc[8]=fmaf(xs,w4.x,acc[8]); acc[9]=fmaf(xs,w4.y,acc[9]); \
  } while (0)

#pragma unroll 2
  for (int g = 0; g < KCH / 4; g++) {
    const int k = k0 + g * 4;
    float xa[4];
    if (k < GR) {
      float4 xv = *(const float4*)(xr + (size_t)b * GR + k);
      xa[0] = xv.x; xa[1] = xv.y; xa[2] = xv.z; xa[3] = xv.w;
    } else {
      const int mi = k - GR;
      const float* hp = hm + (size_t)mi * BATCH + b;
      const int lk = g * 4;
#pragma unroll
      for (int j = 0; j < 4; j++)
        xa[j] = fmaf(hp[(size_t)j * BATCH], scs[lk + j], shs[lk + j]);
    }
#pragma unroll
    for (int j = 0; j < 4; j++) FMA10(xa[j], g * 4 + j);
  }
#undef FMA10

  const size_t base = ((size_t)kc * BATCH + b) * ORR + ob;
#pragma unroll
  for (int j = 0; j < 10; j++)
    if (j < 8 || full) pw[base + j] = acc[j];
}

// ---------------- root finalize: sum partials + bias + tanh + BN partials ---
__global__ __launch_bounds__(256) void k_rootfinal(
    const float* __restrict__ pw, const float* __restrict__ bias,
    float* __restrict__ hr, float* __restrict__ rp)
{
  const int blk = blockIdx.x;     // 0..31
  const int t = threadIdx.x;
  const int w = t >> 6, lane = t & 63;
  const int ob = w * 10;
  const bool full = (w < 3);
  const int b = blk * 64 + lane;

  float acc[10];
#pragma unroll
  for (int j = 0; j < 10; j++) acc[j] = 0.f;

#pragma unroll 1
  for (int kc = 0; kc < KSPLIT; kc++) {
    const size_t base = ((size_t)kc * BATCH + b) * ORR + ob;
#pragma unroll
    for (int j = 0; j < 10; j++)
      if (j < 8 || full) acc[j] += pw[base + j];
  }

#pragma unroll
  for (int j = 0; j < 10; j++) {
    float bj = (j < 8 || full) ? bias[ob + j] : 0.f;
    acc[j] = tanh_fast(acc[j] + bj);
  }

#pragma unroll
  for (int j = 0; j < 10; j++) {
    float s1 = acc[j], s2 = acc[j] * acc[j];
#pragma unroll
    for (int d = 32; d >= 1; d >>= 1) { s1 += __shfl_xor(s1, d); s2 += __shfl_xor(s2, d); }
    if (lane == 0 && (j < 8 || full)) {
      rp[blk * 76 + ob + j] = s1;
      rp[blk * 76 + ORR + ob + j] = s2;
    }
  }
#pragma unroll
  for (int j = 0; j < 10; j++)
    if (j < 8 || full) hr[(size_t)b * ORR + ob + j] = acc[j];
}

// ---------------- root BN finalize -> output --------------------------------
__global__ __launch_bounds__(256) void k_rootnorm(
    const float* __restrict__ hr, const float* __restrict__ rp,
    const float* __restrict__ g, const float* __restrict__ be,
    float* __restrict__ out)
{
  __shared__ float sc[ORR], sh[ORR];
  const int t = threadIdx.x;
  if (t < ORR) {
    float s1 = 0.f, s2 = 0.f;
    for (int blk = 0; blk < 32; blk++) {
      s1 += rp[blk * 76 + t];
      s2 += rp[blk * 76 + ORR + t];
    }
    float mean = s1 * (1.f / BATCH);
    float var  = s2 * (1.f / BATCH) - mean * mean;
    float r = rsqrtf(var + EPSBN);
    float scv = g[t] * r;
    sc[t] = scv;
    sh[t] = be[t] - mean * scv;
  }
  __syncthreads();
  const int idx = blockIdx.x * 256 + t;   // 304*256 = 77824 exactly
  const int o = idx % ORR;
  out[idx] = hr[idx] * sc[o] + sh[o];
}

extern "C" void kernel_launch(void* const* d_in, const int* in_sizes, int n_in,
                              void* d_out, int out_size, void* d_ws, size_t ws_size,
                              hipStream_t stream) {
  (void)in_sizes; (void)n_in; (void)out_size; (void)ws_size;
  const float* x_leaf  = (const float*)d_in[0];
  const float* x_mid   = (const float*)d_in[1];
  const float* x_root  = (const float*)d_in[2];
  const float* W_leaf  = (const float*)d_in[3];
  const float* b_leaf  = (const float*)d_in[4];
  const float* g_leaf  = (const float*)d_in[5];
  const float* be_leaf = (const float*)d_in[6];
  const float* W_mid   = (const float*)d_in[7];
  const float* b_mid   = (const float*)d_in[8];
  const float* g_mid   = (const float*)d_in[9];
  const float* be_mid  = (const float*)d_in[10];
  const float* W_root  = (const float*)d_in[11];
  const float* b_root  = (const float*)d_in[12];
  const float* g_root  = (const float*)d_in[13];
  const float* be_root = (const float*)d_in[14];
  float* out = (float*)d_out;
  float* ws  = (float*)d_ws;

  float* child = ws;
  float* scL   = ws + OFF_SCL;
  float* shL   = ws + OFF_SHL;
  float* hm    = ws + OFF_HM;
  float* mp    = ws + OFF_MP;
  float* hr    = ws + OFF_HR;
  float* rp    = ws + OFF_RP;
  float* scm   = ws + OFF_SCM;
  float* shm   = ws + OFF_SHM;
  float* pw    = ws + OFF_PW;
  float* lp    = ws + OFF_LP;

  k_leaf<<<dim3(8, SS), 256, 0, stream>>>(x_leaf, W_leaf, b_leaf, child, lp);
  k_leafstats<<<40, 256, 0, stream>>>(lp, g_leaf, be_leaf, scL, shL);
  k_mid<<<dim3(32, MM), 256, 0, stream>>>(x_mid, child, scL, shL, W_mid, b_mid,
                                          hm, mp);
  k_midstats<<<3, 256, 0, stream>>>(mp, g_mid, be_mid, scm, shm);
  k_root_partial<<<dim3(32, KSPLIT), 256, 0, stream>>>(x_root, hm, scm, shm,
                                                       W_root, pw);
  k_rootfinal<<<32, 256, 0, stream>>>(pw, b_root, hr, rp);
  k_rootnorm<<<304, 256, 0, stream>>>(hr, rp, g_root, be_root, out);
}